// Round 6
// baseline (440.250 us; speedup 1.0000x reference)
//
#include <hip/hip_runtime.h>

#define NTAG 64
#define SOS_T 61
#define EOS_T 62
#define BB 512
#define SS 1024
#define WAVES 8
#define LOG2E 1.4426950408889634f
#define LN2   0.6931471805599453f

typedef __fp16 h2f __attribute__((ext_vector_type(2)));

// fmax with a DPP-shuffled copy of x (VALU-only cross-lane, no DS pipe).
template<int CTRL>
__device__ __forceinline__ float dppfmax(float x) {
    int xi = __float_as_int(x);
    int yi = __builtin_amdgcn_update_dpp(xi, xi, CTRL, 0xf, 0xf, false);
    return fmaxf(x, __int_as_float(yi));
}

// One wave per batch row; lane = tag; 8 waves/block -> 2 waves/SIMD (TLP
// fills readlane hazard stalls). Exp-space forward recursion:
//   A_new[j] = ef[t,j] * sum_i A[i]*expT[i][j]
// Broadcast: pack (A[2i],A[2i+1]) as f16x2 via DPP+cvt_pkrtz, 32 readlanes
// -> SGPRs, 32 v_dot2_f32_f16 (f32 accumulate). Normalization: delay-1
// deadbeat feedback via DPP fmax tree (off the critical chain); exact pow2
// bookkeeping in Mf. No DS/LDS ops in the main loop.
#define STEP(EF, MK) do {                                                    \
    int Ai_ = __float_as_int(A);                                             \
    int nb_ = __builtin_amdgcn_update_dpp(Ai_, Ai_, 0xB1, 0xf, 0xf, false);  \
    h2f pr_ = __builtin_amdgcn_cvt_pkrtz(A, __int_as_float(nb_));            \
    int pri_; __builtin_memcpy(&pri_, &pr_, 4);                              \
    float q0_ = 0.f, q1_ = 0.f, q2_ = 0.f, q3_ = 0.f;                        \
    _Pragma("unroll")                                                        \
    for (int s_ = 0; s_ < 32; ++s_) {                                        \
        int bp_ = __builtin_amdgcn_readlane(pri_, 2 * s_);                   \
        h2f av_; __builtin_memcpy(&av_, &bp_, 4);                            \
        switch (s_ & 3) {                                                    \
            case 0: q0_ = __builtin_amdgcn_fdot2(av_, eT2h[s_], q0_, false); break; \
            case 1: q1_ = __builtin_amdgcn_fdot2(av_, eT2h[s_], q1_, false); break; \
            case 2: q2_ = __builtin_amdgcn_fdot2(av_, eT2h[s_], q2_, false); break; \
            default: q3_ = __builtin_amdgcn_fdot2(av_, eT2h[s_], q3_, false); break; \
        }                                                                    \
    }                                                                        \
    float qq_ = (q0_ + q1_) + (q2_ + q3_);                                   \
    float An_ = qq_ * ((EF) * sc1);                                          \
    A = ((MK) != 0.f) ? An_ : A;                                             \
    Mf = fmaf((MK), e1, Mf);                                                 \
    float mx_ = dppfmax<0xB1>(A);      /* quad_perm 1,0,3,2 */               \
    mx_ = dppfmax<0x4E>(mx_);          /* quad_perm 2,3,0,1 */               \
    mx_ = dppfmax<0x141>(mx_);         /* row_half_mirror   */               \
    mx_ = dppfmax<0x140>(mx_);         /* row_mirror        */               \
    mx_ = dppfmax<0x142>(mx_);         /* row_bcast15       */               \
    mx_ = dppfmax<0x143>(mx_);         /* row_bcast31 -> lane63 global */    \
    int me_ = (__builtin_amdgcn_readlane(__float_as_int(mx_), 63) >> 23) - 127; \
    sc1 = __int_as_float((127 - me_) << 23);                                 \
    e1  = (float)me_;                                                        \
} while (0)

__global__ __launch_bounds__(512) void crf_nll_kernel(
    const float* __restrict__ emissions,  // [B,S,64]
    const int*   __restrict__ tags,       // [B,S]
    const float* __restrict__ mask,       // [B,S]
    const float* __restrict__ trans,      // [64,64]
    float* __restrict__ out)              // [1]
{
    const int widx = threadIdx.x >> 6;
    const int j    = threadIdx.x & 63;    // tag index = lane
    const int b    = blockIdx.x * WAVES + widx;

    __shared__ __align__(16) float T_lds[NTAG * NTAG];

    // ---- stage transitions cooperatively (block-wide) ----
    const float4* tg4 = (const float4*)trans;
    float4* tl4 = (float4*)T_lds;
#pragma unroll
    for (int i = 0; i < 2; ++i) tl4[i * 512 + threadIdx.x] = tg4[i * 512 + threadIdx.x];

    // exp(T) column j as f16 pairs (i-pairs) in regs
    h2f eT2h[32];
#pragma unroll
    for (int i = 0; i < 32; ++i) {
        float x = exp2f(trans[(2 * i + 0) * NTAG + j] * LOG2E);  // -1e6 -> exactly 0
        float y = exp2f(trans[(2 * i + 1) * NTAG + j] * LOG2E);
        eT2h[i] = __builtin_amdgcn_cvt_pkrtz(x, y);
    }
    __syncthreads();   // once, prologue only

    const float* emb_g = emissions + (size_t)b * SS * NTAG;
    const int*   tgb   = tags + (size_t)b * SS;
    const float* mkb   = mask + (size_t)b * SS;

    // ---- gold-path score + msum, lane-parallel over time (wave-local) ----
    float sc = 0.f, ms = 0.f;
#pragma unroll 4
    for (int k = 0; k < SS / 64; ++k) {
        int t = k * 64 + j;
        int tg = tgb[t];
        float m = mkb[t];
        ms += m;
        float e = emb_g[t * NTAG + tg];
        if (t == 0) {
            sc += T_lds[SOS_T * NTAG + tg] + e;
        } else {
            int tgp = tgb[t - 1];
            sc += m * (e + T_lds[tgp * NTAG + tg]);
        }
    }
#pragma unroll
    for (int o = 32; o > 0; o >>= 1) {
        sc += __shfl_xor(sc, o);
        ms += __shfl_xor(ms, o);
    }
    int last_idx = (int)(ms + 0.5f) - 1;
    int last_tag = tgb[last_idx];
    sc += T_lds[last_tag * NTAG + EOS_T];

    // hoist finalize constants out of LDS
    float tEOSj = T_lds[j * NTAG + EOS_T];

    // ---- t=0 init ----
    float A = exp2f((T_lds[SOS_T * NTAG + j] + emb_g[j]) * LOG2E);
    float Mf  = 0.f;    // accumulated pow2 exponent (exact integer floats)
    float sc1 = 1.0f;   // pending normalization scale 2^-e(A_{t-1})
    float e1  = 0.0f;   // its exponent

    // ---- prefetch rings, depth 16: emissions (vector) + mask (uniform) ----
    float er[16], mr[16];
#pragma unroll
    for (int k = 0; k < 16; ++k) {
        er[k] = emb_g[(1 + k) * NTAG + j];
        mr[k] = mkb[1 + k];
    }

    // ---- main recursion: 63 groups of 16 (t = 1..1008), then 15-step tail ----
#pragma unroll 1
    for (int tb = 1; tb <= SS - 31; tb += 16) {
        float ef[16], mkc[16];
#pragma unroll
        for (int k = 0; k < 16; ++k) {
            ef[k]  = exp2f(er[k] * LOG2E);
            mkc[k] = mr[k];
        }
#pragma unroll
        for (int k = 0; k < 16; ++k) {
            int tn = tb + 16 + k;
            tn = (tn > SS - 1) ? (SS - 1) : tn;
            er[k] = emb_g[tn * NTAG + j];
            mr[k] = mkb[tn];
        }
        STEP(ef[0],  mkc[0]);
        STEP(ef[1],  mkc[1]);
        STEP(ef[2],  mkc[2]);
        STEP(ef[3],  mkc[3]);
        STEP(ef[4],  mkc[4]);
        STEP(ef[5],  mkc[5]);
        STEP(ef[6],  mkc[6]);
        STEP(ef[7],  mkc[7]);
        STEP(ef[8],  mkc[8]);
        STEP(ef[9],  mkc[9]);
        STEP(ef[10], mkc[10]);
        STEP(ef[11], mkc[11]);
        STEP(ef[12], mkc[12]);
        STEP(ef[13], mkc[13]);
        STEP(ef[14], mkc[14]);
        STEP(ef[15], mkc[15]);
    }
    {   // tail: t = 1009..1023 (15 steps, rings hold them)
        float ef[15], mkc[15];
#pragma unroll
        for (int k = 0; k < 15; ++k) {
            ef[k]  = exp2f(er[k] * LOG2E);
            mkc[k] = mr[k];
        }
        STEP(ef[0],  mkc[0]);
        STEP(ef[1],  mkc[1]);
        STEP(ef[2],  mkc[2]);
        STEP(ef[3],  mkc[3]);
        STEP(ef[4],  mkc[4]);
        STEP(ef[5],  mkc[5]);
        STEP(ef[6],  mkc[6]);
        STEP(ef[7],  mkc[7]);
        STEP(ef[8],  mkc[8]);
        STEP(ef[9],  mkc[9]);
        STEP(ef[10], mkc[10]);
        STEP(ef[11], mkc[11]);
        STEP(ef[12], mkc[12]);
        STEP(ef[13], mkc[13]);
        STEP(ef[14], mkc[14]);
    }

    // ---- finalize: log_z = ( log2( sum_j A[j]*exp(T[j][EOS]) ) + Mf ) * ln2 ----
    float val = A * exp2f(tEOSj * LOG2E);
#pragma unroll
    for (int o = 32; o > 0; o >>= 1) val += __shfl_xor(val, o);
    float log_z = (log2f(val) + Mf) * LN2;

    if (j == 0) atomicAdd(out, log_z - sc);
}

extern "C" void kernel_launch(void* const* d_in, const int* in_sizes, int n_in,
                              void* d_out, int out_size, void* d_ws, size_t ws_size,
                              hipStream_t stream) {
    const float* emissions = (const float*)d_in[0];
    const int*   tags      = (const int*)d_in[1];
    const float* mask      = (const float*)d_in[2];
    const float* trans     = (const float*)d_in[3];
    float* out = (float*)d_out;

    hipMemsetAsync(out, 0, sizeof(float), stream);
    crf_nll_kernel<<<dim3(BB / WAVES), dim3(512), 0, stream>>>(emissions, tags, mask, trans, out);
}

// Round 7
// 385.364 us; speedup vs baseline: 1.1424x; 1.1424x over previous
//
#include <hip/hip_runtime.h>

#define NTAG 64
#define SOS_T 61
#define EOS_T 62
#define BB 512
#define SS 1024
#define LOG2E 1.4426950408889634f
#define LN2   0.6931471805599453f

// fmax with a DPP-shuffled copy of x (VALU-only cross-lane, no DS pipe).
template<int CTRL>
__device__ __forceinline__ float dppfmax(float x) {
    int xi = __float_as_int(x);
    int yi = __builtin_amdgcn_update_dpp(xi, xi, CTRL, 0xf, 0xf, false);
    return fmaxf(x, __int_as_float(yi));
}

// 8 readlanes grouped, THEN 8 fmacs: the v_readlane (VALU->SGPR) result is
// consumed >=14 cy after its write, so the VALU->SGPR->VALU wait-state
// hazard (~4-5 cy, paid per pair when interleaved r,f,r,f) vanishes.
// Hard-ordered inside one asm block so the scheduler cannot re-interleave.
#define DOT8(ACC, EBASE, L0,L1,L2,L3,L4,L5,L6,L7)                            \
  { int t0_,t1_,t2_,t3_,t4_,t5_,t6_,t7_;                                     \
    asm("v_readlane_b32 %[t0], %[va], %[l0]\n\t"                             \
        "v_readlane_b32 %[t1], %[va], %[l1]\n\t"                             \
        "v_readlane_b32 %[t2], %[va], %[l2]\n\t"                             \
        "v_readlane_b32 %[t3], %[va], %[l3]\n\t"                             \
        "v_readlane_b32 %[t4], %[va], %[l4]\n\t"                             \
        "v_readlane_b32 %[t5], %[va], %[l5]\n\t"                             \
        "v_readlane_b32 %[t6], %[va], %[l6]\n\t"                             \
        "v_readlane_b32 %[t7], %[va], %[l7]\n\t"                             \
        "v_fmac_f32 %[acc], %[t0], %[e0]\n\t"                                \
        "v_fmac_f32 %[acc], %[t1], %[e1]\n\t"                                \
        "v_fmac_f32 %[acc], %[t2], %[e2]\n\t"                                \
        "v_fmac_f32 %[acc], %[t3], %[e3]\n\t"                                \
        "v_fmac_f32 %[acc], %[t4], %[e4]\n\t"                                \
        "v_fmac_f32 %[acc], %[t5], %[e5]\n\t"                                \
        "v_fmac_f32 %[acc], %[t6], %[e6]\n\t"                                \
        "v_fmac_f32 %[acc], %[t7], %[e7]"                                    \
        : [acc]"+v"(ACC),                                                    \
          [t0]"=&s"(t0_), [t1]"=&s"(t1_), [t2]"=&s"(t2_), [t3]"=&s"(t3_),    \
          [t4]"=&s"(t4_), [t5]"=&s"(t5_), [t6]"=&s"(t6_), [t7]"=&s"(t7_)     \
        : [va]"v"(A),                                                        \
          [e0]"v"(eT[(EBASE)+0]), [e1]"v"(eT[(EBASE)+1]),                    \
          [e2]"v"(eT[(EBASE)+2]), [e3]"v"(eT[(EBASE)+3]),                    \
          [e4]"v"(eT[(EBASE)+4]), [e5]"v"(eT[(EBASE)+5]),                    \
          [e6]"v"(eT[(EBASE)+6]), [e7]"v"(eT[(EBASE)+7]),                    \
          [l0]"i"(L0), [l1]"i"(L1), [l2]"i"(L2), [l3]"i"(L3),                \
          [l4]"i"(L4), [l5]"i"(L5), [l6]"i"(L6), [l7]"i"(L7));               \
  }

// One wave per batch row; lane = tag. Exp-space forward recursion:
//   A_new[j] = ef[t,j] * sum_i A[i]*expT[i][j]
// Broadcast via grouped readlanes (above). Normalization: delay-1 deadbeat
// feedback via DPP fmax tree (consumed one full step later -> off-chain);
// exact pow2 bookkeeping in Mf. No DS/LDS ops in the main loop.
#define STEP(EF, MK) do {                                                    \
    float a0_=0.f,a1_=0.f,a2_=0.f,a3_=0.f,a4_=0.f,a5_=0.f,a6_=0.f,a7_=0.f;   \
    DOT8(a0_,  0,  0, 1, 2, 3, 4, 5, 6, 7);                                  \
    DOT8(a1_,  8,  8, 9,10,11,12,13,14,15);                                  \
    DOT8(a2_, 16, 16,17,18,19,20,21,22,23);                                  \
    DOT8(a3_, 24, 24,25,26,27,28,29,30,31);                                  \
    DOT8(a4_, 32, 32,33,34,35,36,37,38,39);                                  \
    DOT8(a5_, 40, 40,41,42,43,44,45,46,47);                                  \
    DOT8(a6_, 48, 48,49,50,51,52,53,54,55);                                  \
    DOT8(a7_, 56, 56,57,58,59,60,61,62,63);                                  \
    float qq_ = ((a0_+a1_)+(a2_+a3_)) + ((a4_+a5_)+(a6_+a7_));               \
    float An_ = qq_ * ((EF) * sc1);                                          \
    A = ((MK) != 0.f) ? An_ : A;                                             \
    Mf = fmaf((MK), e1, Mf);                                                 \
    float mx_ = dppfmax<0xB1>(A);      /* quad_perm 1,0,3,2 */               \
    mx_ = dppfmax<0x4E>(mx_);          /* quad_perm 2,3,0,1 */               \
    mx_ = dppfmax<0x141>(mx_);         /* row_half_mirror   */               \
    mx_ = dppfmax<0x140>(mx_);         /* row_mirror        */               \
    mx_ = dppfmax<0x142>(mx_);         /* row_bcast15       */               \
    mx_ = dppfmax<0x143>(mx_);         /* row_bcast31 -> lane63 global */    \
    int me_ = (__builtin_amdgcn_readlane(__float_as_int(mx_), 63) >> 23) - 127; \
    sc1 = __int_as_float((127 - me_) << 23);                                 \
    e1  = (float)me_;                                                        \
} while (0)

__global__ __launch_bounds__(64) void crf_nll_kernel(
    const float* __restrict__ emissions,  // [B,S,64]
    const int*   __restrict__ tags,       // [B,S]
    const float* __restrict__ mask,       // [B,S]
    const float* __restrict__ trans,      // [64,64]
    float* __restrict__ out)              // [1]
{
    const int b = blockIdx.x;
    const int j = threadIdx.x;            // tag index = lane

    __shared__ __align__(16) float T_lds[NTAG * NTAG];

    // ---- stage transitions: raw copy to LDS (score lookups), exp(T) col j in regs ----
    const float4* tg4 = (const float4*)trans;
    float4* tl4 = (float4*)T_lds;
#pragma unroll
    for (int i = 0; i < 16; ++i) tl4[i * 64 + j] = tg4[i * 64 + j];

    float eT[NTAG];
#pragma unroll
    for (int i = 0; i < NTAG; ++i)
        eT[i] = exp2f(trans[i * NTAG + j] * LOG2E);   // -1e6 -> exactly 0
    __syncthreads();   // once, prologue only

    const float* emb_g = emissions + (size_t)b * SS * NTAG;
    const int*   tgb   = tags + (size_t)b * SS;
    const float* mkb   = mask + (size_t)b * SS;

    // ---- gold-path score + msum, lane-parallel over time ----
    float sc = 0.f, ms = 0.f;
#pragma unroll 4
    for (int k = 0; k < SS / 64; ++k) {
        int t = k * 64 + j;
        int tg = tgb[t];
        float m = mkb[t];
        ms += m;
        float e = emb_g[t * NTAG + tg];
        if (t == 0) {
            sc += T_lds[SOS_T * NTAG + tg] + e;
        } else {
            int tgp = tgb[t - 1];
            sc += m * (e + T_lds[tgp * NTAG + tg]);
        }
    }
#pragma unroll
    for (int o = 32; o > 0; o >>= 1) {
        sc += __shfl_xor(sc, o);
        ms += __shfl_xor(ms, o);
    }
    int last_idx = (int)(ms + 0.5f) - 1;
    int last_tag = tgb[last_idx];
    sc += T_lds[last_tag * NTAG + EOS_T];

    float tEOSj = T_lds[j * NTAG + EOS_T];

    // ---- t=0 init ----
    float A = exp2f((T_lds[SOS_T * NTAG + j] + emb_g[j]) * LOG2E);
    float Mf  = 0.f;    // accumulated pow2 exponent (exact integer floats)
    float sc1 = 1.0f;   // pending normalization scale 2^-e(A_{t-1})
    float e1  = 0.0f;   // its exponent

    // ---- prefetch rings, depth 16: emissions (vector) + mask (uniform) ----
    float er[16], mr[16];
#pragma unroll
    for (int k = 0; k < 16; ++k) {
        er[k] = emb_g[(1 + k) * NTAG + j];
        mr[k] = mkb[1 + k];
    }

    // ---- main recursion: 63 groups of 16 (t = 1..1008), then 15-step tail ----
#pragma unroll 1
    for (int tb = 1; tb <= SS - 31; tb += 16) {
        float ef[16], mkc[16];
#pragma unroll
        for (int k = 0; k < 16; ++k) {
            ef[k]  = exp2f(er[k] * LOG2E);
            mkc[k] = mr[k];
        }
#pragma unroll
        for (int k = 0; k < 16; ++k) {
            int tn = tb + 16 + k;
            tn = (tn > SS - 1) ? (SS - 1) : tn;
            er[k] = emb_g[tn * NTAG + j];
            mr[k] = mkb[tn];
        }
        STEP(ef[0],  mkc[0]);
        STEP(ef[1],  mkc[1]);
        STEP(ef[2],  mkc[2]);
        STEP(ef[3],  mkc[3]);
        STEP(ef[4],  mkc[4]);
        STEP(ef[5],  mkc[5]);
        STEP(ef[6],  mkc[6]);
        STEP(ef[7],  mkc[7]);
        STEP(ef[8],  mkc[8]);
        STEP(ef[9],  mkc[9]);
        STEP(ef[10], mkc[10]);
        STEP(ef[11], mkc[11]);
        STEP(ef[12], mkc[12]);
        STEP(ef[13], mkc[13]);
        STEP(ef[14], mkc[14]);
        STEP(ef[15], mkc[15]);
    }
    {   // tail: t = 1009..1023 (15 steps, rings hold them)
        float ef[15], mkc[15];
#pragma unroll
        for (int k = 0; k < 15; ++k) {
            ef[k]  = exp2f(er[k] * LOG2E);
            mkc[k] = mr[k];
        }
        STEP(ef[0],  mkc[0]);
        STEP(ef[1],  mkc[1]);
        STEP(ef[2],  mkc[2]);
        STEP(ef[3],  mkc[3]);
        STEP(ef[4],  mkc[4]);
        STEP(ef[5],  mkc[5]);
        STEP(ef[6],  mkc[6]);
        STEP(ef[7],  mkc[7]);
        STEP(ef[8],  mkc[8]);
        STEP(ef[9],  mkc[9]);
        STEP(ef[10], mkc[10]);
        STEP(ef[11], mkc[11]);
        STEP(ef[12], mkc[12]);
        STEP(ef[13], mkc[13]);
        STEP(ef[14], mkc[14]);
    }

    // ---- finalize: log_z = ( log2( sum_j A[j]*exp(T[j][EOS]) ) + Mf ) * ln2 ----
    float val = A * exp2f(tEOSj * LOG2E);
#pragma unroll
    for (int o = 32; o > 0; o >>= 1) val += __shfl_xor(val, o);
    float log_z = (log2f(val) + Mf) * LN2;

    if (j == 0) atomicAdd(out, log_z - sc);
}

extern "C" void kernel_launch(void* const* d_in, const int* in_sizes, int n_in,
                              void* d_out, int out_size, void* d_ws, size_t ws_size,
                              hipStream_t stream) {
    const float* emissions = (const float*)d_in[0];
    const int*   tags      = (const int*)d_in[1];
    const float* mask      = (const float*)d_in[2];
    const float* trans     = (const float*)d_in[3];
    float* out = (float*)d_out;

    hipMemsetAsync(out, 0, sizeof(float), stream);
    crf_nll_kernel<<<dim3(BB), dim3(64), 0, stream>>>(emissions, tags, mask, trans, out);
}